// Round 9
// baseline (135.252 us; speedup 1.0000x reference)
//
#include <hip/hip_runtime.h>
#include <hip/hip_bf16.h>

// DIAGNOSTIC ROUND: exact R8 body, replicated x5 via blockIdx.z (replicas write
// identical values -> output unchanged). Purpose: (a) kernel cost = (total-floor)/5,
// (b) push the kernel above the ~44us fill dispatches so it surfaces in rocprof
// top-5 WITH counters (spill/FETCH, LDS conflicts, VALUBusy/MfmaUtil/Occupancy).

#define NPTS   300
#define HW_SZ  1920
#define NH     8
#define TOTAL  (NPTS * HW_SZ)    // 576000
#define NCOL   2400              // columns c = n*8 + h
#define L2T128 0.10381025293350249f   // log2(10000)/128

#define BM  64
#define BN  64
#define LDK 72                   // padded LDS k-stride (shorts)
#define SNP 129                  // sn/cn padded stride (floats)
#define WLP 17                   // wl padded row stride (floats)
#define MT  (HW_SZ / BM)         // 30
#define CT  38                   // 2432 / 64
#define REP 5                    // diagnostic replication factor

typedef __attribute__((ext_vector_type(8))) short short8;
typedef __attribute__((ext_vector_type(4))) float floatx4;

__device__ __forceinline__ unsigned bf16_rne(float x) {
    unsigned u = __float_as_uint(x);
    return (u + 0x7fffu + ((u >> 16) & 1u)) >> 16;
}

__global__ __launch_bounds__(256, 4) void dre_diag(const float* __restrict__ pd,
                                                   const float* __restrict__ dm,
                                                   const float* __restrict__ W,
                                                   const float* __restrict__ b,
                                                   float* __restrict__ out)
{
    __shared__ float kf[128];
    __shared__ float ldm[BM];
    __shared__ float sn[8 * SNP];
    __shared__ float cn[8 * SNP];
    __shared__ float wl[128 * WLP];
    __shared__ unsigned short As[BM * LDK];
    __shared__ unsigned short Bs[BN * LDK];

    const int tid = threadIdx.x;
    const int m0  = blockIdx.x * BM;
    const int c0  = blockIdx.y * BN;
    const int n0  = c0 >> 3;

    // ---- setup: kf, ldm, wl ----
    if (tid < 128)      kf[tid] = 100.0f * exp2f(-(float)tid * L2T128);
    else if (tid < 192) ldm[tid - 128] = __logf(dm[m0 + tid - 128] + 1e-5f);
    {
        const int i = tid >> 1, half = tid & 1;
#pragma unroll
        for (int j = 0; j < 8; ++j)
            wl[i * WLP + half * 8 + j] = W[i * 16 + half * 8 + j];
    }
    __syncthreads();

    // ---- sn/cn for 8 n's ----
    {
        const int nl = tid >> 5;
        const int nn = n0 + nl;
        const float pv = (nn < NPTS) ? pd[nn] : 0.0f;
        const float lp = __logf(fmaxf(pv, 0.0f) + 1e-5f);
#pragma unroll
        for (int j = 0; j < 4; ++j) {
            const int i = (tid & 31) * 4 + j;
            float s, c;
            __sincosf(kf[i] * lp, &s, &c);
            sn[nl * SNP + i] = s;
            cn[nl * SNP + i] = c;
        }
    }

    const int w    = tid >> 6;
    const int lane = tid & 63;
    const int quad = lane >> 4;
    const int l16  = lane & 15;

    const int arow = tid >> 2;
    const int akb  = (tid & 3) * 16;
    const int bcr  = tid >> 2;
    const int bkb  = (tid & 3) * 16;
    const int bnl  = bcr >> 3;
    const int bh   = bcr & 7;

    floatx4 acc[4];
#pragma unroll
    for (int nf = 0; nf < 4; ++nf) acc[nf] = (floatx4){0.f, 0.f, 0.f, 0.f};

    unsigned stash[2][8];

    __syncthreads();
    const float ld = ldm[arow];

#pragma unroll
    for (int ch = 0; ch < 4; ++ch) {
        const int ibase = (ch & 1) * 64;
        if (ch < 2) {
            unsigned uc[8];
#pragma unroll
            for (int g = 0; g < 8; ++g) {
                const int i = ibase + akb + 2 * g;
                float s0, c0v, s1, c1v;
                __sincosf(kf[i] * ld,     &s0, &c0v);
                __sincosf(kf[i + 1] * ld, &s1, &c1v);
                uc[g]        = bf16_rne(c0v) | (bf16_rne(c1v) << 16);
                stash[ch][g] = bf16_rne(s0)  | (bf16_rne(s1)  << 16);
            }
            *(uint4*)&As[arow * LDK + akb]     = make_uint4(uc[0], uc[1], uc[2], uc[3]);
            *(uint4*)&As[arow * LDK + akb + 8] = make_uint4(uc[4], uc[5], uc[6], uc[7]);
        } else {
            const unsigned* st = stash[ch - 2];
            *(uint4*)&As[arow * LDK + akb]     = make_uint4(st[0], st[1], st[2], st[3]);
            *(uint4*)&As[arow * LDK + akb + 8] = make_uint4(st[4], st[5], st[6], st[7]);
        }
        {
            unsigned uq[8];
#pragma unroll
            for (int g = 0; g < 8; ++g) {
                const int i = ibase + bkb + 2 * g;
                const float s0  = sn[bnl * SNP + i],     cc0 = cn[bnl * SNP + i];
                const float s1  = sn[bnl * SNP + i + 1], cc1 = cn[bnl * SNP + i + 1];
                const float ws0 = wl[i * WLP + bh],       wc0 = wl[i * WLP + 8 + bh];
                const float ws1 = wl[(i+1) * WLP + bh],   wc1 = wl[(i+1) * WLP + 8 + bh];
                float v0, v1;
                if (ch < 2) { v0 = ws0*s0 + wc0*cc0; v1 = ws1*s1 + wc1*cc1; }
                else        { v0 = wc0*s0 - ws0*cc0; v1 = wc1*s1 - ws1*cc1; }
                uq[g] = bf16_rne(v0) | (bf16_rne(v1) << 16);
            }
            *(uint4*)&Bs[bcr * LDK + bkb]     = make_uint4(uq[0], uq[1], uq[2], uq[3]);
            *(uint4*)&Bs[bcr * LDK + bkb + 8] = make_uint4(uq[4], uq[5], uq[6], uq[7]);
        }
        __syncthreads();

#pragma unroll
        for (int ks = 0; ks < 2; ++ks) {
            const int koff = ks * 32 + quad * 8;
            short8 a0 = *(const short8*)(&As[(w * 16 + l16) * LDK + koff]);
#pragma unroll
            for (int nf = 0; nf < 4; ++nf) {
                short8 bb = *(const short8*)(&Bs[(nf * 16 + l16) * LDK + koff]);
                acc[nf] = __builtin_amdgcn_mfma_f32_16x16x32_bf16(a0, bb, acc[nf], 0, 0, 0);
            }
        }
        __syncthreads();
    }

    const float bias = b[lane & 7];
#pragma unroll
    for (int nf = 0; nf < 4; ++nf) {
        const int c = c0 + nf * 16 + l16;
        if (c < NCOL) {
            const int n = c >> 3, h = c & 7;
            const int hw = m0 + w * 16 + quad * 4;
            floatx4 v = acc[nf];
            v.x = fmaxf(v.x + bias, 0.0f);
            v.y = fmaxf(v.y + bias, 0.0f);
            v.z = fmaxf(v.z + bias, 0.0f);
            v.w = fmaxf(v.w + bias, 0.0f);
            *(floatx4*)(out + (size_t)h * TOTAL + (size_t)n * HW_SZ + hw) = v;
        }
    }
}

extern "C" void kernel_launch(void* const* d_in, const int* in_sizes, int n_in,
                              void* d_out, int out_size, void* d_ws, size_t ws_size,
                              hipStream_t stream) {
    const float* pd = (const float*)d_in[0];
    const float* dm = (const float*)d_in[1];
    const float* W  = (const float*)d_in[2];
    const float* b  = (const float*)d_in[3];
    float* out = (float*)d_out;

    // x5 replication along z: all replicas compute & store identical values.
    dre_diag<<<dim3(MT, CT, REP), 256, 0, stream>>>(pd, dm, W, b, out);
}

// Round 10
// 78.084 us; speedup vs baseline: 1.7321x; 1.7321x over previous
//
#include <hip/hip_runtime.h>
#include <hip/hip_bf16.h>

#define NPTS   300
#define HW_SZ  1920
#define TOTAL  (NPTS * HW_SZ)    // 576000
#define NCOL   2400              // columns c = n*8 + h
#define L2T128 0.10381025293350249f   // log2(10000)/128

#define BM  64
#define BN  64
#define LDK 72                   // Bs k-stride (shorts), 144 B rows (16B-aligned)
#define SNP 132                  // sn/cn row stride (floats), 528 B (16B-aligned)
#define WTP 132                  // wst/wct row stride (floats)
#define MT  30
#define CT  38

typedef __attribute__((ext_vector_type(8))) short short8;
typedef __attribute__((ext_vector_type(4))) float floatx4;

union frag_u { unsigned u[4]; short8 s; };

// pack two f32 -> bf16 pair (round-half-up): 2 v_add + 1 v_perm
__device__ __forceinline__ unsigned pk_bf16(float lo, float hi) {
    return __builtin_amdgcn_perm(__float_as_uint(hi) + 0x8000u,
                                 __float_as_uint(lo) + 0x8000u,
                                 0x07060302u);
}

// out[hw, c] = relu( sum_i cos(k_i ld)*P[i,c] + sin(k_i ld)*Q[i,c] + b[h] )
//   P = Ws*sin(k lp) + Wc*cos(k lp),  Q = Wc*sin(k lp) - Ws*cos(k lp)
// A-fragments computed register-direct (no As LDS); B vectorized via float4
// reads of sn/cn and transposed W; Q + A-sin stashed for the sin-chunks.
__global__ __launch_bounds__(256, 4) void dre_v10(const float* __restrict__ pd,
                                                  const float* __restrict__ dm,
                                                  const float* __restrict__ W,
                                                  const float* __restrict__ b,
                                                  float* __restrict__ out)
{
    __shared__ float kfr[128];                 //  0.5 KB
    __shared__ float ldm[BM];                  // 0.25 KB
    __shared__ float snq[8 * SNP];             //  4.2 KB
    __shared__ float cnq[8 * SNP];             //  4.2 KB
    __shared__ float wst[8 * WTP];             //  4.2 KB  Ws transposed [h][i]
    __shared__ float wct[8 * WTP];             //  4.2 KB  Wc transposed [h][i]
    __shared__ unsigned short Bs[2][BN * LDK]; // 18.4 KB  double-buffered
                                               // => ~36 KB, 4 blk/CU

    const int tid = threadIdx.x;
    const int m0  = blockIdx.x * BM;
    const int c0  = blockIdx.y * BN;
    const int n0  = c0 >> 3;

    // ---- setup: kfr, ldm, W-transpose, sn/cn ----
    if (tid < 128)      kfr[tid] = 100.0f * exp2f(-(float)tid * L2T128);
    else if (tid < 192) ldm[tid - 128] = __logf(dm[m0 + tid - 128] + 1e-5f);
#pragma unroll
    for (int v = 0; v < 8; ++v) {              // 2048 vals: [arr][h][i]
        const int lin = tid * 8 + v;
        const int arr = lin >> 10, rest = lin & 1023;
        const int h = rest >> 7, i = rest & 127;
        const float val = W[i * 16 + arr * 8 + h];
        (arr ? wct : wst)[h * WTP + i] = val;
    }
    {
        const int nl = tid >> 5;               // 0..7
        const int nn = n0 + nl;
        const float pv = (nn < NPTS) ? pd[nn] : 0.0f;   // pad n masked at store
        const float lp = __logf(fmaxf(pv, 0.0f) + 1e-5f);
#pragma unroll
        for (int j = 0; j < 4; ++j) {
            const int i = (tid & 31) * 4 + j;
            const float k = 100.0f * exp2f(-(float)i * L2T128); // == kfr[i]
            float s, c;
            __sincosf(k * lp, &s, &c);         // |a| <= 1561 rad < 256 rev
            snq[nl * SNP + i] = s;
            cnq[nl * SNP + i] = c;
        }
    }

    const int w = tid >> 6, lane = tid & 63, quad = lane >> 4, l16 = lane & 15;
    const int bcr = tid >> 2, q = tid & 3;     // B-build: c row, 16-wide k group
    const int bnl = bcr >> 3, bh = bcr & 7;

    floatx4 acc[4];
#pragma unroll
    for (int nf = 0; nf < 4; ++nf) acc[nf] = (floatx4){0.f, 0.f, 0.f, 0.f};

    unsigned astash[2][2][4];                  // packed sin A-frags [ch][ks][reg]
    unsigned qstash[2][8];                     // packed Q rows      [ch][reg]

    __syncthreads();
    const float ld_row = ldm[w * 16 + l16];    // this lane's A row

    // chunks: ch 0,1 = cos/P (i in [0,64),[64,128)); ch 2,3 = sin/Q (same i)
#pragma unroll
    for (int ch = 0; ch < 4; ++ch) {
        const int ibase = (ch & 1) * 64;
        unsigned short* bsb = Bs[ch & 1];
        frag_u af[2];

        if (ch < 2) {
            // ---- B tile: P (+ stash Q), float4-vectorized ----
            unsigned pp[8];
#pragma unroll
            for (int g = 0; g < 4; ++g) {
                const int i4 = ibase + q * 16 + g * 4;
                const float4 s4 = *(const float4*)&snq[bnl * SNP + i4];
                const float4 c4 = *(const float4*)&cnq[bnl * SNP + i4];
                const float4 a4 = *(const float4*)&wst[bh * WTP + i4];
                const float4 o4 = *(const float4*)&wct[bh * WTP + i4];
                const float P0 = a4.x*s4.x + o4.x*c4.x, P1 = a4.y*s4.y + o4.y*c4.y;
                const float P2 = a4.z*s4.z + o4.z*c4.z, P3 = a4.w*s4.w + o4.w*c4.w;
                const float Q0 = o4.x*s4.x - a4.x*c4.x, Q1 = o4.y*s4.y - a4.y*c4.y;
                const float Q2 = o4.z*s4.z - a4.z*c4.z, Q3 = o4.w*s4.w - a4.w*c4.w;
                pp[2*g]   = pk_bf16(P0, P1);
                pp[2*g+1] = pk_bf16(P2, P3);
                qstash[ch][2*g]   = pk_bf16(Q0, Q1);
                qstash[ch][2*g+1] = pk_bf16(Q2, Q3);
            }
            *(uint4*)&bsb[bcr * LDK + q * 16]     = make_uint4(pp[0], pp[1], pp[2], pp[3]);
            *(uint4*)&bsb[bcr * LDK + q * 16 + 8] = make_uint4(pp[4], pp[5], pp[6], pp[7]);

            // ---- A frags register-direct: cos now, sin stashed ----
#pragma unroll
            for (int ks = 0; ks < 2; ++ks) {
                const int kb = ibase + ks * 32 + quad * 8;
                const float4 f0 = *(const float4*)&kfr[kb];      // broadcast
                const float4 f1 = *(const float4*)&kfr[kb + 4];
                float s[8], c[8];
                __sincosf(f0.x * ld_row, &s[0], &c[0]);
                __sincosf(f0.y * ld_row, &s[1], &c[1]);
                __sincosf(f0.z * ld_row, &s[2], &c[2]);
                __sincosf(f0.w * ld_row, &s[3], &c[3]);
                __sincosf(f1.x * ld_row, &s[4], &c[4]);
                __sincosf(f1.y * ld_row, &s[5], &c[5]);
                __sincosf(f1.z * ld_row, &s[6], &c[6]);
                __sincosf(f1.w * ld_row, &s[7], &c[7]);
#pragma unroll
                for (int r = 0; r < 4; ++r) {
                    af[ks].u[r]          = pk_bf16(c[2*r], c[2*r+1]);
                    astash[ch][ks][r]    = pk_bf16(s[2*r], s[2*r+1]);
                }
            }
        } else {
            // ---- sin chunks: everything from stashes ----
            const unsigned* qs = qstash[ch - 2];
            *(uint4*)&bsb[bcr * LDK + q * 16]     = make_uint4(qs[0], qs[1], qs[2], qs[3]);
            *(uint4*)&bsb[bcr * LDK + q * 16 + 8] = make_uint4(qs[4], qs[5], qs[6], qs[7]);
#pragma unroll
            for (int ks = 0; ks < 2; ++ks)
#pragma unroll
                for (int r = 0; r < 4; ++r) af[ks].u[r] = astash[ch - 2][ks][r];
        }

        __syncthreads();   // Bs[ch&1] ready (also guards WAR vs chunk ch-2 reads)

#pragma unroll
        for (int ks = 0; ks < 2; ++ks) {
            const int koff = ks * 32 + quad * 8;
#pragma unroll
            for (int nf = 0; nf < 4; ++nf) {
                short8 bb = *(const short8*)&bsb[(nf * 16 + l16) * LDK + koff];
                acc[nf] = __builtin_amdgcn_mfma_f32_16x16x32_bf16(af[ks].s, bb, acc[nf], 0, 0, 0);
            }
        }
    }

    // ---- epilogue (verified): C/D col=lane&15, row=quad*4+reg ----
    const float bias = b[lane & 7];
#pragma unroll
    for (int nf = 0; nf < 4; ++nf) {
        const int c = c0 + nf * 16 + l16;
        if (c < NCOL) {
            const int n = c >> 3, h = c & 7;
            const int hw = m0 + w * 16 + quad * 4;
            floatx4 v = acc[nf];
            v.x = fmaxf(v.x + bias, 0.0f);
            v.y = fmaxf(v.y + bias, 0.0f);
            v.z = fmaxf(v.z + bias, 0.0f);
            v.w = fmaxf(v.w + bias, 0.0f);
            *(floatx4*)(out + (size_t)h * TOTAL + (size_t)n * HW_SZ + hw) = v;
        }
    }
}

extern "C" void kernel_launch(void* const* d_in, const int* in_sizes, int n_in,
                              void* d_out, int out_size, void* d_ws, size_t ws_size,
                              hipStream_t stream) {
    const float* pd = (const float*)d_in[0];
    const float* dm = (const float*)d_in[1];
    const float* W  = (const float*)d_in[2];
    const float* b  = (const float*)d_in[3];
    float* out = (float*)d_out;

    dre_v10<<<dim3(MT, CT), 256, 0, stream>>>(pd, dm, W, b, out);
}

// Round 11
// 74.504 us; speedup vs baseline: 1.8154x; 1.0480x over previous
//
#include <hip/hip_runtime.h>
#include <hip/hip_bf16.h>

#define NPTS   300
#define HW_SZ  1920
#define TOTAL  (NPTS * HW_SZ)    // 576000
#define NCOL   2400              // columns c = n*8 + h
#define L2T128 0.10381025293350249f   // log2(10000)/128

#define BM   64
#define BN   64
#define LDK2 136                 // BsP/BsQ row stride (shorts): 68 dw == 4 mod 32
#define SNP  132                 // snq/cnq row stride (floats): == 4 mod 32
#define WPP  132                 // wpk row stride (dwords)
#define MT   30
#define CT   38

typedef __attribute__((ext_vector_type(8))) short short8;
typedef __attribute__((ext_vector_type(4))) float floatx4;

union frag_u { unsigned u[4]; short8 s; };

// pack two f32 -> bf16 pair (round-half-up): 2 v_add + 1 v_perm
__device__ __forceinline__ unsigned pk_bf16(float lo, float hi) {
    return __builtin_amdgcn_perm(__float_as_uint(hi) + 0x8000u,
                                 __float_as_uint(lo) + 0x8000u,
                                 0x07060302u);
}
__device__ __forceinline__ float blo(unsigned u) { return __uint_as_float(u << 16); }
__device__ __forceinline__ float bhi(unsigned u) { return __uint_as_float(u & 0xffff0000u); }

// out[hw, c] = relu( sum_i cos(k_i ld)*P[i,c] + sin(k_i ld)*Q[i,c] + b[h] )
//   P = Ws*sin(k lp) + Wc*cos(k lp),  Q = Wc*sin(k lp) - Ws*cos(k lp)
// 2-barrier structure: [setup] | [build P+Q full-width] | [32 MFMA + JIT A-frags].
__global__ __launch_bounds__(256, 4) void dre_v11(const float* __restrict__ pd,
                                                  const float* __restrict__ dm,
                                                  const float* __restrict__ W,
                                                  const float* __restrict__ b,
                                                  float* __restrict__ out)
{
    __shared__ float    kfr[128];            //  0.5 KB
    __shared__ float    ldm[BM];             // 0.25 KB
    __shared__ float    snq[8 * SNP];        //  4.2 KB  sin(k_i lp(n))
    __shared__ float    cnq[8 * SNP];        //  4.2 KB  cos(k_i lp(n))
    __shared__ unsigned wpk[8 * WPP];        //  4.2 KB  (bf16 ws | bf16 wc<<16)[h][i]
    __shared__ unsigned short BsP[BN * LDK2];// 17.4 KB
    __shared__ unsigned short BsQ[BN * LDK2];// 17.4 KB  => ~48 KB, 3 blk/CU

    const int tid = threadIdx.x;
    const int m0  = blockIdx.x * BM;
    const int c0  = blockIdx.y * BN;
    const int n0  = c0 >> 3;

    // ---- setup ----
    if (tid < 128)      kfr[tid] = 100.0f * exp2f(-(float)tid * L2T128);
    else if (tid < 192) ldm[tid - 128] = __logf(dm[m0 + tid - 128] + 1e-5f);
    {   // W -> packed bf16 pairs, transposed [h][i]
        const int h = tid & 7, i0 = (tid >> 3) * 4;   // covers 8 x 128
        unsigned pk[4];
#pragma unroll
        for (int j = 0; j < 4; ++j)
            pk[j] = pk_bf16(W[(i0 + j) * 16 + h], W[(i0 + j) * 16 + 8 + h]);
        *(uint4*)&wpk[h * WPP + i0] = make_uint4(pk[0], pk[1], pk[2], pk[3]);
    }
    {   // sn/cn for the block's 8 n's
        const int nl = tid >> 5, i0 = (tid & 31) * 4;
        const int nn = n0 + nl;
        const float pv = (nn < NPTS) ? pd[nn] : 0.0f;     // pad n masked at store
        const float lp = __logf(fmaxf(pv, 0.0f) + 1e-5f);
        float s[4], c[4];
#pragma unroll
        for (int j = 0; j < 4; ++j) {
            const float k = 100.0f * exp2f(-(float)(i0 + j) * L2T128);
            __sincosf(k * lp, &s[j], &c[j]);              // |a| < 256 rev: v_sin ok
        }
        *(float4*)&snq[nl * SNP + i0] = make_float4(s[0], s[1], s[2], s[3]);
        *(float4*)&cnq[nl * SNP + i0] = make_float4(c[0], c[1], c[2], c[3]);
    }
    __syncthreads();

    // ---- build BsP / BsQ, full i in [0,128), one pass ----
    {
        const int bcr = tid >> 2, q = tid & 3;            // c row, 32-i span
        const int bnl = bcr >> 3, bh = bcr & 7;
#pragma unroll
        for (int half = 0; half < 2; ++half) {
            const int ib0 = q * 32 + half * 16;
            unsigned pp[8], qq[8];
#pragma unroll
            for (int g = 0; g < 4; ++g) {
                const int i4 = ib0 + g * 4;
                const float4 s4 = *(const float4*)&snq[bnl * SNP + i4];
                const float4 c4 = *(const float4*)&cnq[bnl * SNP + i4];
                const uint4  w4 = *(const uint4*)&wpk[bh * WPP + i4];
                const float ws0 = blo(w4.x), wc0 = bhi(w4.x);
                const float ws1 = blo(w4.y), wc1 = bhi(w4.y);
                const float ws2 = blo(w4.z), wc2 = bhi(w4.z);
                const float ws3 = blo(w4.w), wc3 = bhi(w4.w);
                const float P0 = ws0*s4.x + wc0*c4.x, Q0 = wc0*s4.x - ws0*c4.x;
                const float P1 = ws1*s4.y + wc1*c4.y, Q1 = wc1*s4.y - ws1*c4.y;
                const float P2 = ws2*s4.z + wc2*c4.z, Q2 = wc2*s4.z - ws2*c4.z;
                const float P3 = ws3*s4.w + wc3*c4.w, Q3 = wc3*s4.w - ws3*c4.w;
                pp[2*g] = pk_bf16(P0, P1);  pp[2*g+1] = pk_bf16(P2, P3);
                qq[2*g] = pk_bf16(Q0, Q1);  qq[2*g+1] = pk_bf16(Q2, Q3);
            }
            *(uint4*)&BsP[bcr * LDK2 + ib0]     = make_uint4(pp[0], pp[1], pp[2], pp[3]);
            *(uint4*)&BsP[bcr * LDK2 + ib0 + 8] = make_uint4(pp[4], pp[5], pp[6], pp[7]);
            *(uint4*)&BsQ[bcr * LDK2 + ib0]     = make_uint4(qq[0], qq[1], qq[2], qq[3]);
            *(uint4*)&BsQ[bcr * LDK2 + ib0 + 8] = make_uint4(qq[4], qq[5], qq[6], qq[7]);
        }
    }
    __syncthreads();

    // ---- MFMA phase: JIT A-frags (cos+sin), 32 MFMAs, no barriers ----
    const int w = tid >> 6, lane = tid & 63, quad = lane >> 4, l16 = lane & 15;
    const float ld_row = ldm[w * 16 + l16];

    floatx4 acc[4];
#pragma unroll
    for (int nf = 0; nf < 4; ++nf) acc[nf] = (floatx4){0.f, 0.f, 0.f, 0.f};

#pragma unroll
    for (int ib = 0; ib < 2; ++ib) {
        frag_u cf[2], sf[2];
#pragma unroll
        for (int ks = 0; ks < 2; ++ks) {
            const int kb = ib * 64 + ks * 32 + quad * 8;
            const float4 f0 = *(const float4*)&kfr[kb];
            const float4 f1 = *(const float4*)&kfr[kb + 4];
            float s[8], c[8];
            __sincosf(f0.x * ld_row, &s[0], &c[0]);
            __sincosf(f0.y * ld_row, &s[1], &c[1]);
            __sincosf(f0.z * ld_row, &s[2], &c[2]);
            __sincosf(f0.w * ld_row, &s[3], &c[3]);
            __sincosf(f1.x * ld_row, &s[4], &c[4]);
            __sincosf(f1.y * ld_row, &s[5], &c[5]);
            __sincosf(f1.z * ld_row, &s[6], &c[6]);
            __sincosf(f1.w * ld_row, &s[7], &c[7]);
#pragma unroll
            for (int r = 0; r < 4; ++r) {
                cf[ks].u[r] = pk_bf16(c[2*r], c[2*r+1]);
                sf[ks].u[r] = pk_bf16(s[2*r], s[2*r+1]);
            }
        }
#pragma unroll
        for (int ks = 0; ks < 2; ++ks) {
            const int koff = ib * 64 + ks * 32 + quad * 8;
#pragma unroll
            for (int nf = 0; nf < 4; ++nf) {
                short8 bp = *(const short8*)&BsP[(nf * 16 + l16) * LDK2 + koff];
                acc[nf] = __builtin_amdgcn_mfma_f32_16x16x32_bf16(cf[ks].s, bp, acc[nf], 0, 0, 0);
                short8 bq = *(const short8*)&BsQ[(nf * 16 + l16) * LDK2 + koff];
                acc[nf] = __builtin_amdgcn_mfma_f32_16x16x32_bf16(sf[ks].s, bq, acc[nf], 0, 0, 0);
            }
        }
    }

    // ---- epilogue (verified): C/D col=lane&15, row=quad*4+reg ----
    const float bias = b[lane & 7];
#pragma unroll
    for (int nf = 0; nf < 4; ++nf) {
        const int c = c0 + nf * 16 + l16;
        if (c < NCOL) {
            const int n = c >> 3, h = c & 7;
            const int hw = m0 + w * 16 + quad * 4;
            floatx4 v = acc[nf];
            v.x = fmaxf(v.x + bias, 0.0f);
            v.y = fmaxf(v.y + bias, 0.0f);
            v.z = fmaxf(v.z + bias, 0.0f);
            v.w = fmaxf(v.w + bias, 0.0f);
            *(floatx4*)(out + (size_t)h * TOTAL + (size_t)n * HW_SZ + hw) = v;
        }
    }
}

extern "C" void kernel_launch(void* const* d_in, const int* in_sizes, int n_in,
                              void* d_out, int out_size, void* d_ws, size_t ws_size,
                              hipStream_t stream) {
    const float* pd = (const float*)d_in[0];
    const float* dm = (const float*)d_in[1];
    const float* W  = (const float*)d_in[2];
    const float* b  = (const float*)d_in[3];
    float* out = (float*)d_out;

    dre_v11<<<dim3(MT, CT), 256, 0, stream>>>(pd, dm, W, b, out);
}

// Round 12
// 71.858 us; speedup vs baseline: 1.8822x; 1.0368x over previous
//
#include <hip/hip_runtime.h>
#include <hip/hip_bf16.h>

#define NPTS   300
#define HW_SZ  1920
#define TOTAL  (NPTS * HW_SZ)    // 576000
#define NCOL   2400              // columns c = n*8 + h
#define L2T128 0.10381025293350249f   // log2(10000)/128
#define KREVL2 3.9923601817f     // log2(100 / (2*pi))

#define BM   128
#define BN   64
#define LDK2 136                 // BsP/BsQ row stride (shorts)
#define SNP  132                 // snq/cnq row stride (floats)
#define WPP  132                 // wpk row stride (dwords)
#define MT   15                  // 1920 / 128
#define CT   38                  // 2432 / 64

typedef __attribute__((ext_vector_type(8))) short short8;
typedef __attribute__((ext_vector_type(4))) float floatx4;

union frag_u { unsigned u[4]; short8 s; };

// pack two f32 -> bf16 pair (round-half-up): 2 v_add + 1 v_perm
__device__ __forceinline__ unsigned pk_bf16(float lo, float hi) {
    return __builtin_amdgcn_perm(__float_as_uint(hi) + 0x8000u,
                                 __float_as_uint(lo) + 0x8000u,
                                 0x07060302u);
}
__device__ __forceinline__ float blo(unsigned u) { return __uint_as_float(u << 16); }
__device__ __forceinline__ float bhi(unsigned u) { return __uint_as_float(u & 0xffff0000u); }

// All angles in REVOLUTIONS (krev = k/2pi, max |angle| = 248.4 rev < 256 domain):
// raw v_sin_f32 / v_cos_f32, one instruction each.
// out[hw, c] = relu( sum_i cos*P + sin*Q + b[h] );  P,Q from angle-addition.
__global__ __launch_bounds__(256, 3) void dre_v12(const float* __restrict__ pd,
                                                  const float* __restrict__ dm,
                                                  const float* __restrict__ W,
                                                  const float* __restrict__ b,
                                                  float* __restrict__ out)
{
    __shared__ float    kfr[128];            //  0.5 KB  krev[i]
    __shared__ float    ldm[BM];             //  0.5 KB
    __shared__ float    snq[8 * SNP];        //  4.2 KB  sin(krev_i lp(n)) [rev]
    __shared__ float    cnq[8 * SNP];        //  4.2 KB
    __shared__ unsigned wpk[8 * WPP];        //  4.2 KB  (bf16 ws | bf16 wc<<16)[h][i]
    __shared__ unsigned short BsP[BN * LDK2];// 17.4 KB
    __shared__ unsigned short BsQ[BN * LDK2];// 17.4 KB  => 48.4 KB, 3 blk/CU

    const int tid = threadIdx.x;
    const int m0  = blockIdx.x * BM;
    const int c0  = blockIdx.y * BN;
    const int n0  = c0 >> 3;

    // ---- setup ----
    if (tid < 128)      kfr[tid] = exp2f(KREVL2 - (float)tid * L2T128);
    else                ldm[tid - 128 + 64] = __logf(dm[m0 + tid - 64] + 1e-5f);
    if (tid < 64)       ldm[tid] = __logf(dm[m0 + tid] + 1e-5f);
    {   // W -> packed bf16 pairs, transposed [h][i]
        const int h = tid & 7, i0 = (tid >> 3) * 4;
        unsigned pk[4];
#pragma unroll
        for (int j = 0; j < 4; ++j)
            pk[j] = pk_bf16(W[(i0 + j) * 16 + h], W[(i0 + j) * 16 + 8 + h]);
        *(uint4*)&wpk[h * WPP + i0] = make_uint4(pk[0], pk[1], pk[2], pk[3]);
    }
    {   // sn/cn for the block's 8 n's (angles in revolutions)
        const int nl = tid >> 5, i0 = (tid & 31) * 4;
        const int nn = n0 + nl;
        const float pv = (nn < NPTS) ? pd[nn] : 0.0f;     // pad n masked at store
        const float lp = __logf(fmaxf(pv, 0.0f) + 1e-5f);
        float s[4], c[4];
#pragma unroll
        for (int j = 0; j < 4; ++j) {
            const float a = exp2f(KREVL2 - (float)(i0 + j) * L2T128) * lp;
            s[j] = __builtin_amdgcn_sinf(a);
            c[j] = __builtin_amdgcn_cosf(a);
        }
        *(float4*)&snq[nl * SNP + i0] = make_float4(s[0], s[1], s[2], s[3]);
        *(float4*)&cnq[nl * SNP + i0] = make_float4(c[0], c[1], c[2], c[3]);
    }
    __syncthreads();

    // ---- build BsP / BsQ, full i in [0,128), one pass ----
    {
        const int bcr = tid >> 2, q = tid & 3;            // c row, 32-i span
        const int bnl = bcr >> 3, bh = bcr & 7;
#pragma unroll
        for (int half = 0; half < 2; ++half) {
            const int ib0 = q * 32 + half * 16;
            unsigned pp[8], qq[8];
#pragma unroll
            for (int g = 0; g < 4; ++g) {
                const int i4 = ib0 + g * 4;
                const float4 s4 = *(const float4*)&snq[bnl * SNP + i4];
                const float4 c4 = *(const float4*)&cnq[bnl * SNP + i4];
                const uint4  w4 = *(const uint4*)&wpk[bh * WPP + i4];
                const float ws0 = blo(w4.x), wc0 = bhi(w4.x);
                const float ws1 = blo(w4.y), wc1 = bhi(w4.y);
                const float ws2 = blo(w4.z), wc2 = bhi(w4.z);
                const float ws3 = blo(w4.w), wc3 = bhi(w4.w);
                const float P0 = ws0*s4.x + wc0*c4.x, Q0 = wc0*s4.x - ws0*c4.x;
                const float P1 = ws1*s4.y + wc1*c4.y, Q1 = wc1*s4.y - ws1*c4.y;
                const float P2 = ws2*s4.z + wc2*c4.z, Q2 = wc2*s4.z - ws2*c4.z;
                const float P3 = ws3*s4.w + wc3*c4.w, Q3 = wc3*s4.w - ws3*c4.w;
                pp[2*g] = pk_bf16(P0, P1);  pp[2*g+1] = pk_bf16(P2, P3);
                qq[2*g] = pk_bf16(Q0, Q1);  qq[2*g+1] = pk_bf16(Q2, Q3);
            }
            *(uint4*)&BsP[bcr * LDK2 + ib0]     = make_uint4(pp[0], pp[1], pp[2], pp[3]);
            *(uint4*)&BsP[bcr * LDK2 + ib0 + 8] = make_uint4(pp[4], pp[5], pp[6], pp[7]);
            *(uint4*)&BsQ[bcr * LDK2 + ib0]     = make_uint4(qq[0], qq[1], qq[2], qq[3]);
            *(uint4*)&BsQ[bcr * LDK2 + ib0 + 8] = make_uint4(qq[4], qq[5], qq[6], qq[7]);
        }
    }
    __syncthreads();

    // ---- MFMA phase: JIT A-frags, 64 MFMAs (2 M-subtiles), no barriers ----
    const int w = tid >> 6, lane = tid & 63, quad = lane >> 4, l16 = lane & 15;
    const float ldr0 = ldm[w * 32 + l16];
    const float ldr1 = ldm[w * 32 + 16 + l16];

    floatx4 acc[2][4];
#pragma unroll
    for (int mi = 0; mi < 2; ++mi)
#pragma unroll
        for (int nf = 0; nf < 4; ++nf) acc[mi][nf] = (floatx4){0.f, 0.f, 0.f, 0.f};

#pragma unroll
    for (int ib = 0; ib < 2; ++ib) {
        frag_u cf[2][2], sf[2][2];                        // [mi][ks]
#pragma unroll
        for (int ks = 0; ks < 2; ++ks) {
            const int kb = ib * 64 + ks * 32 + quad * 8;
            const float4 f0 = *(const float4*)&kfr[kb];
            const float4 f1 = *(const float4*)&kfr[kb + 4];
            const float fr[8] = {f0.x, f0.y, f0.z, f0.w, f1.x, f1.y, f1.z, f1.w};
            float s0[8], c0v[8], s1[8], c1v[8];
#pragma unroll
            for (int j = 0; j < 8; ++j) {
                const float a0 = fr[j] * ldr0;            // revolutions
                const float a1 = fr[j] * ldr1;
                s0[j]  = __builtin_amdgcn_sinf(a0);
                c0v[j] = __builtin_amdgcn_cosf(a0);
                s1[j]  = __builtin_amdgcn_sinf(a1);
                c1v[j] = __builtin_amdgcn_cosf(a1);
            }
#pragma unroll
            for (int r = 0; r < 4; ++r) {
                cf[0][ks].u[r] = pk_bf16(c0v[2*r], c0v[2*r+1]);
                sf[0][ks].u[r] = pk_bf16(s0[2*r],  s0[2*r+1]);
                cf[1][ks].u[r] = pk_bf16(c1v[2*r], c1v[2*r+1]);
                sf[1][ks].u[r] = pk_bf16(s1[2*r],  s1[2*r+1]);
            }
        }
#pragma unroll
        for (int ks = 0; ks < 2; ++ks) {
            const int koff = ib * 64 + ks * 32 + quad * 8;
#pragma unroll
            for (int nf = 0; nf < 4; ++nf) {
                short8 bp = *(const short8*)&BsP[(nf * 16 + l16) * LDK2 + koff];
                acc[0][nf] = __builtin_amdgcn_mfma_f32_16x16x32_bf16(cf[0][ks].s, bp, acc[0][nf], 0, 0, 0);
                acc[1][nf] = __builtin_amdgcn_mfma_f32_16x16x32_bf16(cf[1][ks].s, bp, acc[1][nf], 0, 0, 0);
                short8 bq = *(const short8*)&BsQ[(nf * 16 + l16) * LDK2 + koff];
                acc[0][nf] = __builtin_amdgcn_mfma_f32_16x16x32_bf16(sf[0][ks].s, bq, acc[0][nf], 0, 0, 0);
                acc[1][nf] = __builtin_amdgcn_mfma_f32_16x16x32_bf16(sf[1][ks].s, bq, acc[1][nf], 0, 0, 0);
            }
        }
    }

    // ---- epilogue (verified, R4's BM=128 form): C/D col=lane&15, row=quad*4+reg ----
    const float bias = b[lane & 7];
#pragma unroll
    for (int mi = 0; mi < 2; ++mi) {
#pragma unroll
        for (int nf = 0; nf < 4; ++nf) {
            const int c = c0 + nf * 16 + l16;
            if (c < NCOL) {
                const int n = c >> 3, h = c & 7;
                const int hw = m0 + w * 32 + mi * 16 + quad * 4;
                floatx4 v = acc[mi][nf];
                v.x = fmaxf(v.x + bias, 0.0f);
                v.y = fmaxf(v.y + bias, 0.0f);
                v.z = fmaxf(v.z + bias, 0.0f);
                v.w = fmaxf(v.w + bias, 0.0f);
                *(floatx4*)(out + (size_t)h * TOTAL + (size_t)n * HW_SZ + hw) = v;
            }
        }
    }
}

extern "C" void kernel_launch(void* const* d_in, const int* in_sizes, int n_in,
                              void* d_out, int out_size, void* d_ws, size_t ws_size,
                              hipStream_t stream) {
    const float* pd = (const float*)d_in[0];
    const float* dm = (const float*)d_in[1];
    const float* W  = (const float*)d_in[2];
    const float* b  = (const float*)d_in[3];
    float* out = (float*)d_out;

    dre_v12<<<dim3(MT, CT), 256, 0, stream>>>(pd, dm, W, b, out);
}